// Round 2
// baseline (531.256 us; speedup 1.0000x reference)
//
#include <hip/hip_runtime.h>
#include <cstdint>

// ---------------------------------------------------------------------------
// DirGraphSAGE round 10b (compile fix of r10):
//  - 4B fused edge payload: (u << 16) | deg(u). N=50000 < 2^16 so u fits in
//    16 bits; weight recovered in-kernel as 1.0f/(float)deg (IEEE div ->
//    bit-identical to the old fp32 table). Halves the ep stream: agg fetch
//    -12.8 MB/dispatch, and halves k_fill's scattered payload bytes.
//  - nontemporal loads on the ep stream + nontemporal stores on agg output:
//    both are single-use streams; keeping them out of L2 preserves residency
//    for the random 256B x-row gathers (the actual L2-miss BW bottleneck).
//    (fix: use ext_vector_type for the 16B nt load/store — the builtin
//    rejects HIP_vector_type classes.)
//  - rankf/rankb packed 16+16 into one array (-6.4 MB preprocessing traffic).
//  - inv_in/inv_out arrays dropped entirely (degrees travel in the payload).
//  - k_agg6 structure otherwise unchanged (16 lanes/node, 4 nodes/wave,
//    unroll x2); row-major bf16 everywhere; split-W MFMA GEMM unchanged.
// ---------------------------------------------------------------------------

typedef __bf16 bf16x8 __attribute__((ext_vector_type(8)));
typedef float f32x4 __attribute__((ext_vector_type(4)));
typedef unsigned u32x4 __attribute__((ext_vector_type(4)));

__device__ __forceinline__ unsigned short f2bf(float f) {
  unsigned u = __float_as_uint(f);
  u += 0x7FFFu + ((u >> 16) & 1u);   // round-to-nearest-even
  return (unsigned short)(u >> 16);
}
__device__ __forceinline__ float bflo(unsigned u) { return __uint_as_float(u << 16); }
__device__ __forceinline__ float bfhi(unsigned u) { return __uint_as_float(u & 0xFFFF0000u); }

// Padded counters: one 4B counter per 64B line (stride 16 ints).
// Ranks packed 16|16 into one array (rank < 2^16 since max degree << 2^16).
__global__ __launch_bounds__(256) void k_degrees(const int* __restrict__ src,
                                                 const int* __restrict__ dst,
                                                 int* __restrict__ cin_p,
                                                 int* __restrict__ cout_p,
                                                 unsigned* __restrict__ rank_pk, int E) {
  int e = blockIdx.x * 256 + threadIdx.x;
  if (e >= E) return;
  int s = __builtin_nontemporal_load(&src[e]);
  int d = __builtin_nontemporal_load(&dst[e]);
  unsigned rf = (unsigned)atomicAdd(&cin_p[(size_t)d * 16], 1);   // rank in fwd list (by dst)
  unsigned rb = (unsigned)atomicAdd(&cout_p[(size_t)s * 16], 1);  // rank in bwd list (by src)
  __builtin_nontemporal_store((rf & 0xFFFFu) | (rb << 16), &rank_pk[e]);
}

// Compact padded counters to dense arrays for the scan (inv factors no longer
// materialized: degree travels inside the edge payload).
__global__ __launch_bounds__(256) void k_compact(const int* __restrict__ cin_p,
                                                 const int* __restrict__ cout_p,
                                                 int* __restrict__ cin_d,
                                                 int* __restrict__ cout_d, int n) {
  int i = blockIdx.x * 256 + threadIdx.x;
  if (i >= n) return;
  cin_d[i] = cin_p[(size_t)i * 16];
  cout_d[i] = cout_p[(size_t)i * 16];
}

// --- 3-phase multi-block exclusive scan (CHUNK=2048/block, y-dim = which array)
__global__ __launch_bounds__(256) void k_scan_part(const int* __restrict__ cntA,
                                                   const int* __restrict__ cntB,
                                                   int* __restrict__ partA,
                                                   int* __restrict__ partB, int n) {
  const int* cnt = blockIdx.y ? cntB : cntA;
  int* part = blockIdx.y ? partB : partA;
  __shared__ int red[256];
  int t = threadIdx.x;
  int base = blockIdx.x * 2048 + t * 8;
  int s = 0;
#pragma unroll
  for (int i = 0; i < 8; ++i) {
    int idx = base + i;
    if (idx < n) s += cnt[idx];
  }
  red[t] = s;
  __syncthreads();
  for (int o = 128; o > 0; o >>= 1) {
    if (t < o) red[t] += red[t + o];
    __syncthreads();
  }
  if (t == 0) part[blockIdx.x] = red[0];
}

__global__ __launch_bounds__(64) void k_scan_tops(int* __restrict__ partA,
                                                  int* __restrict__ partB, int nb) {
  int* part = blockIdx.y ? partB : partA;
  if (threadIdx.x == 0) {
    int run = 0;
    for (int i = 0; i < nb; ++i) { int v = part[i]; part[i] = run; run += v; }
  }
}

__global__ __launch_bounds__(256) void k_scan_out(const int* __restrict__ cntA,
                                                  const int* __restrict__ cntB,
                                                  const int* __restrict__ partA,
                                                  const int* __restrict__ partB,
                                                  int* __restrict__ offA,
                                                  int* __restrict__ offB, int n) {
  const int* cnt = blockIdx.y ? cntB : cntA;
  const int* part = blockIdx.y ? partB : partA;
  int* off = blockIdx.y ? offB : offA;
  __shared__ int ts[256];
  int t = threadIdx.x;
  int base = blockIdx.x * 2048 + t * 8;
  int v[8];
  int s = 0;
#pragma unroll
  for (int i = 0; i < 8; ++i) {
    int idx = base + i;
    int c = (idx < n) ? cnt[idx] : 0;
    v[i] = s;          // exclusive prefix within thread
    s += c;
  }
  ts[t] = s;
  __syncthreads();
  for (int o = 1; o < 256; o <<= 1) {
    int val = (t >= o) ? ts[t - o] : 0;
    __syncthreads();
    ts[t] += val;
    __syncthreads();
  }
  int blockbase = part[blockIdx.x] + (t ? ts[t - 1] : 0);
#pragma unroll
  for (int i = 0; i < 8; ++i) {
    int idx = base + i;
    if (idx <= n) off[idx] = blockbase + v[i];   // idx==n writes the total
  }
}

// Atomic-free fill; writes fused 4B edge payload (u<<16 | deg(u)).
__global__ __launch_bounds__(256) void k_fill(const int* __restrict__ src,
                                              const int* __restrict__ dst,
                                              const int* __restrict__ offf,
                                              const int* __restrict__ offb,
                                              const unsigned* __restrict__ rank_pk,
                                              const int* __restrict__ cout_d,
                                              const int* __restrict__ cin_d,
                                              unsigned* __restrict__ epf,
                                              unsigned* __restrict__ epb, int E) {
  int e = blockIdx.x * 256 + threadIdx.x;
  if (e >= E) return;
  int s = __builtin_nontemporal_load(&src[e]);
  int d = __builtin_nontemporal_load(&dst[e]);
  unsigned rp = __builtin_nontemporal_load(&rank_pk[e]);
  int rf = (int)(rp & 0xFFFFu), rb = (int)(rp >> 16);
  unsigned co = (unsigned)cout_d[s]; if (co > 65535u) co = 65535u;
  unsigned ci = (unsigned)cin_d[d];  if (ci > 65535u) ci = 65535u;
  epf[offf[d] + rf] = ((unsigned)s << 16) | co;   // weight = 1/out_deg(s)
  epb[offb[s] + rb] = ((unsigned)d << 16) | ci;   // weight = 1/in_deg(d)
}

// x (fp32, N x 128) -> xbu row-major packed bf16x2 (32 uint2 per row)
__global__ __launch_bounds__(256) void k_conv(const float* __restrict__ x,
                                              unsigned* __restrict__ xbu, int n) {
  int idx = blockIdx.x * 256 + threadIdx.x;  // over n*32 float4s
  if (idx >= n * 32) return;
  f32x4 xv = __builtin_nontemporal_load(&((const f32x4*)x)[idx]);
  unsigned u0 = (unsigned)f2bf(xv.x) | ((unsigned)f2bf(xv.y) << 16);
  unsigned u1 = (unsigned)f2bf(xv.z) | ((unsigned)f2bf(xv.w) << 16);
  ((uint2*)xbu)[idx] = make_uint2(u0, u1);
}

// W (fp32 384x128) -> Wt_hi, Wt_lo (bf16, 128x384, transposed, packed x2)
__global__ __launch_bounds__(256) void k_wconv3(
    const float* __restrict__ Wa, const float* __restrict__ Wb,
    const float* __restrict__ Wc,
    unsigned* __restrict__ Ha, unsigned* __restrict__ Hb, unsigned* __restrict__ Hc,
    unsigned* __restrict__ La, unsigned* __restrict__ Lb, unsigned* __restrict__ Lc) {
  const float* W = (blockIdx.y == 0) ? Wa : ((blockIdx.y == 1) ? Wb : Wc);
  unsigned* Wth = (blockIdx.y == 0) ? Ha : ((blockIdx.y == 1) ? Hb : Hc);
  unsigned* Wtl = (blockIdx.y == 0) ? La : ((blockIdx.y == 1) ? Lb : Lc);
  int t = blockIdx.x * 256 + threadIdx.x;   // 128*192 threads; t = j*192 + k2
  if (t >= 128 * 192) return;
  int j = t / 192, k2 = t - j * 192;
  int k = k2 * 2;
  float w0 = W[k * 128 + j], w1 = W[(k + 1) * 128 + j];
  unsigned short h0 = f2bf(w0), h1 = f2bf(w1);
  float l0 = w0 - __uint_as_float((unsigned)h0 << 16);
  float l1 = w1 - __uint_as_float((unsigned)h1 << 16);
  Wth[t] = (unsigned)h0 | ((unsigned)h1 << 16);
  Wtl[t] = (unsigned)f2bf(l0) | ((unsigned)f2bf(l1) << 16);
}

// Single-pass row-major aggregation. 16 lanes/node (uint4 col c), 4 nodes/wave.
// grid: x = node blocks (16 nodes/block), y = dir. ep payload = (u<<16|deg);
// weight recomputed as exact fp32 divide (bit-identical to a table lookup).
// nt loads on ep stream, nt stores on output: keep L2 for the x gathers.
__global__ __launch_bounds__(256) void k_agg6(const uint4* __restrict__ xb,
                                              const int* __restrict__ offA,
                                              const unsigned* __restrict__ epA,
                                              const int* __restrict__ offB,
                                              const unsigned* __restrict__ epB,
                                              uint4* __restrict__ outA,
                                              uint4* __restrict__ outB, int n) {
  int lane = threadIdx.x & 63;
  int gi = lane >> 4, c = lane & 15;     // node-in-wave, uint4 column
  int node = ((blockIdx.x * 256 + threadIdx.x) >> 6) * 4 + gi;
  if (node >= n) return;
  const int* off = blockIdx.y ? offB : offA;
  const unsigned* ep = blockIdx.y ? epB : epA;
  uint4* out = blockIdx.y ? outB : outA;

  int i = off[node], end = off[node + 1];
  float acc[8];
#pragma unroll
  for (int k = 0; k < 8; ++k) acc[k] = 0.f;

  for (; i + 1 < end; i += 2) {
    unsigned e0 = __builtin_nontemporal_load(&ep[i]);
    unsigned e1 = __builtin_nontemporal_load(&ep[i + 1]);
    uint4 r0 = xb[(size_t)(e0 >> 16) * 16 + c];
    uint4 r1 = xb[(size_t)(e1 >> 16) * 16 + c];
    float w0 = 1.0f / (float)(e0 & 0xFFFFu);   // IEEE div: bit-exact vs table
    float w1 = 1.0f / (float)(e1 & 0xFFFFu);
    acc[0] = fmaf(bflo(r0.x), w0, acc[0]); acc[1] = fmaf(bfhi(r0.x), w0, acc[1]);
    acc[2] = fmaf(bflo(r0.y), w0, acc[2]); acc[3] = fmaf(bfhi(r0.y), w0, acc[3]);
    acc[4] = fmaf(bflo(r0.z), w0, acc[4]); acc[5] = fmaf(bfhi(r0.z), w0, acc[5]);
    acc[6] = fmaf(bflo(r0.w), w0, acc[6]); acc[7] = fmaf(bfhi(r0.w), w0, acc[7]);
    acc[0] = fmaf(bflo(r1.x), w1, acc[0]); acc[1] = fmaf(bfhi(r1.x), w1, acc[1]);
    acc[2] = fmaf(bflo(r1.y), w1, acc[2]); acc[3] = fmaf(bfhi(r1.y), w1, acc[3]);
    acc[4] = fmaf(bflo(r1.z), w1, acc[4]); acc[5] = fmaf(bfhi(r1.z), w1, acc[5]);
    acc[6] = fmaf(bflo(r1.w), w1, acc[6]); acc[7] = fmaf(bfhi(r1.w), w1, acc[7]);
  }
  if (i < end) {
    unsigned e0 = __builtin_nontemporal_load(&ep[i]);
    uint4 r0 = xb[(size_t)(e0 >> 16) * 16 + c];
    float w0 = 1.0f / (float)(e0 & 0xFFFFu);
    acc[0] = fmaf(bflo(r0.x), w0, acc[0]); acc[1] = fmaf(bfhi(r0.x), w0, acc[1]);
    acc[2] = fmaf(bflo(r0.y), w0, acc[2]); acc[3] = fmaf(bfhi(r0.y), w0, acc[3]);
    acc[4] = fmaf(bflo(r0.z), w0, acc[4]); acc[5] = fmaf(bfhi(r0.z), w0, acc[5]);
    acc[6] = fmaf(bflo(r0.w), w0, acc[6]); acc[7] = fmaf(bfhi(r0.w), w0, acc[7]);
  }

  uint4 o;
  o.x = (unsigned)f2bf(acc[0]) | ((unsigned)f2bf(acc[1]) << 16);
  o.y = (unsigned)f2bf(acc[2]) | ((unsigned)f2bf(acc[3]) << 16);
  o.z = (unsigned)f2bf(acc[4]) | ((unsigned)f2bf(acc[5]) << 16);
  o.w = (unsigned)f2bf(acc[6]) | ((unsigned)f2bf(acc[7]) << 16);
  u32x4 ov;
  ov.x = o.x; ov.y = o.y; ov.z = o.z; ov.w = o.w;
  __builtin_nontemporal_store(ov, (u32x4*)&out[(size_t)node * 16 + c]);
}

// MFMA GEMM: h = bias + [xbu|fwdb|bwdb][v,:] @ (W_hi + W_lo)   (row-major A)
// If outb: write bf16(relu(h)) row-major (next layer's xbu). Else fp32 outf.
__global__ __launch_bounds__(256) void k_gemm(const unsigned* __restrict__ xbu,
                                              const unsigned* __restrict__ fwdb,
                                              const unsigned* __restrict__ bwdb,
                                              const unsigned* __restrict__ Wth,
                                              const unsigned* __restrict__ Wtl,
                                              const float* __restrict__ bias,
                                              unsigned short* __restrict__ outb,
                                              float* __restrict__ outf, int n) {
  __shared__ uint4 sA[512];    // 8 KB: A chunk, frag order [mt][q][m]
  __shared__ uint4 sWh[512];   // 8 KB
  __shared__ uint4 sWl[512];   // 8 KB
  int tid = threadIdx.x;
  int bm0 = blockIdx.x * 128;
  int w = tid >> 6, lane = tid & 63;

  f32x4 acc[2][8];
#pragma unroll
  for (int mt = 0; mt < 2; ++mt)
#pragma unroll
    for (int nt = 0; nt < 8; ++nt) acc[mt][nt] = (f32x4){0.f, 0.f, 0.f, 0.f};

  const uint4* Wh4 = (const uint4*)Wth;   // row j: 48 uint4 (384 bf16)
  const uint4* Wl4 = (const uint4*)Wtl;

  for (int kc = 0; kc < 12; ++kc) {
    const uint4* src4 = (const uint4*)((kc < 4) ? xbu : ((kc < 8) ? fwdb : bwdb));
    int ko = (kc & 3) * 4;   // uint4 offset within row (16 uint4 = 128 bf16)
    __syncthreads();
#pragma unroll
    for (int p = 0; p < 2; ++p) {
      int f = tid + p * 256;          // 0..511
      int r = f >> 2, q = f & 3;      // r: row/col-of-W, q: k-quad
      int slot = (r >> 4) * 64 + q * 16 + (r & 15);
      int v = bm0 + r;
      uint4 val = make_uint4(0u, 0u, 0u, 0u);
      if (v < n) val = src4[(size_t)v * 16 + ko + q];
      sA[slot] = val;
      sWh[slot] = Wh4[(size_t)r * 48 + kc * 4 + q];
      sWl[slot] = Wl4[(size_t)r * 48 + kc * 4 + q];
    }
    __syncthreads();
    bf16x8 a0 = ((const bf16x8*)sA)[(2 * w) * 64 + lane];
    bf16x8 a1 = ((const bf16x8*)sA)[(2 * w + 1) * 64 + lane];
#pragma unroll
    for (int nt = 0; nt < 8; ++nt) {
      bf16x8 bh = ((const bf16x8*)sWh)[nt * 64 + lane];
      bf16x8 bl = ((const bf16x8*)sWl)[nt * 64 + lane];
      acc[0][nt] = __builtin_amdgcn_mfma_f32_16x16x32_bf16(a0, bh, acc[0][nt], 0, 0, 0);
      acc[0][nt] = __builtin_amdgcn_mfma_f32_16x16x32_bf16(a0, bl, acc[0][nt], 0, 0, 0);
      acc[1][nt] = __builtin_amdgcn_mfma_f32_16x16x32_bf16(a1, bh, acc[1][nt], 0, 0, 0);
      acc[1][nt] = __builtin_amdgcn_mfma_f32_16x16x32_bf16(a1, bl, acc[1][nt], 0, 0, 0);
    }
  }

  // Epilogue. C layout: col = lane&15, row = (lane>>4)*4 + reg  (m89-verified)
  int col = lane & 15;
  float bv[8];
#pragma unroll
  for (int nt = 0; nt < 8; ++nt) bv[nt] = bias[nt * 16 + col];
#pragma unroll
  for (int mt = 0; mt < 2; ++mt) {
    int rowbase = bm0 + w * 32 + mt * 16 + (lane >> 4) * 4;
#pragma unroll
    for (int reg = 0; reg < 4; ++reg) {
      int row = rowbase + reg;
      if (row >= n) continue;
      if (outb) {
#pragma unroll
        for (int nt = 0; nt < 8; ++nt) {
          float t = fmaxf(acc[mt][nt][reg] + bv[nt], 0.f);   // relu layers
          outb[(size_t)row * 128 + nt * 16 + col] = f2bf(t);
        }
      } else {
#pragma unroll
        for (int nt = 0; nt < 8; ++nt) {
          float t = acc[mt][nt][reg] + bv[nt];
          outf[(size_t)row * 128 + nt * 16 + col] = t;
        }
      }
    }
  }
}

extern "C" void kernel_launch(void* const* d_in, const int* in_sizes, int n_in,
                              void* d_out, int out_size, void* d_ws, size_t ws_size,
                              hipStream_t stream) {
  const int D = 128;
  const int N = in_sizes[0] / D;
  const int E = in_sizes[7];

  const float* x  = (const float*)d_in[0];
  const float* W0 = (const float*)d_in[1];
  const float* b0 = (const float*)d_in[2];
  const float* W1 = (const float*)d_in[3];
  const float* b1 = (const float*)d_in[4];
  const float* W2 = (const float*)d_in[5];
  const float* b2 = (const float*)d_in[6];
  const int* src  = (const int*)d_in[7];
  const int* dst  = (const int*)d_in[8];
  float* out = (float*)d_out;

  char* p = (char*)d_ws;
  auto alloc = [&](size_t bytes) -> char* {
    char* r = p;
    p += (bytes + 15) & ~(size_t)15;
    return r;
  };
  int* cin_p  = (int*)alloc((size_t)N * 64);   // padded: 1 counter / 64B line
  int* cout_p = (int*)alloc((size_t)N * 64);
  int* cin_d  = (int*)alloc((size_t)N * 4);    // dense for scan + payload build
  int* cout_d = (int*)alloc((size_t)N * 4);
  int* offf = (int*)alloc((size_t)(N + 1) * 4);
  int* offb = (int*)alloc((size_t)(N + 1) * 4);
  unsigned* rank_pk = (unsigned*)alloc((size_t)E * 4);   // rankf | rankb<<16
  unsigned* epf = (unsigned*)alloc((size_t)E * 4);       // (u<<16 | deg) payload
  unsigned* epb = (unsigned*)alloc((size_t)E * 4);
  unsigned* xbu = (unsigned*)alloc((size_t)N * 64 * 4);  // row-major bf16x2
  unsigned* fwdb = (unsigned*)alloc((size_t)N * 64 * 4);
  unsigned* bwdb = (unsigned*)alloc((size_t)N * 64 * 4);
  unsigned* Wth[3], *Wtl[3];
  for (int l = 0; l < 3; ++l) {
    Wth[l] = (unsigned*)alloc((size_t)128 * 192 * 4);
    Wtl[l] = (unsigned*)alloc((size_t)128 * 192 * 4);
  }
  int nbScan = (N + 1 + 2047) / 2048;
  int* partA = (int*)alloc((size_t)(nbScan + 1) * 4);
  int* partB = (int*)alloc((size_t)(nbScan + 1) * 4);

  hipMemsetAsync(cin_p, 0, (size_t)2 * N * 64, stream);  // cin_p+cout_p contiguous

  k_degrees<<<(E + 255) / 256, 256, 0, stream>>>(src, dst, cin_p, cout_p,
                                                 rank_pk, E);
  k_compact<<<(N + 255) / 256, 256, 0, stream>>>(cin_p, cout_p, cin_d, cout_d, N);
  k_scan_part<<<dim3(nbScan, 2), 256, 0, stream>>>(cin_d, cout_d, partA, partB, N);
  k_scan_tops<<<dim3(1, 2), 64, 0, stream>>>(partA, partB, nbScan);
  k_scan_out<<<dim3(nbScan, 2), 256, 0, stream>>>(cin_d, cout_d, partA, partB,
                                                  offf, offb, N);
  k_fill<<<(E + 255) / 256, 256, 0, stream>>>(src, dst, offf, offb, rank_pk,
                                              cout_d, cin_d, epf, epb, E);
  k_wconv3<<<dim3((128 * 192 + 255) / 256, 3), 256, 0, stream>>>(
      W0, W1, W2, Wth[0], Wth[1], Wth[2], Wtl[0], Wtl[1], Wtl[2]);

  const float* bs[3] = {b0, b1, b2};
  int aggBlocks = (N + 15) / 16;          // 16 nodes/block (4 waves); dir = y
  int convBlocks = (N * 32 + 255) / 256;
  int gemmBlocks = (N + 127) / 128;

  k_conv<<<convBlocks, 256, 0, stream>>>(x, xbu, N);   // layer-0 input only
  for (int l = 0; l < 3; ++l) {
    k_agg6<<<dim3(aggBlocks, 2), 256, 0, stream>>>(
        (const uint4*)xbu, offf, epf, offb, epb,
        (uint4*)fwdb, (uint4*)bwdb, N);
    if (l < 2) {
      k_gemm<<<gemmBlocks, 256, 0, stream>>>(xbu, fwdb, bwdb, Wth[l], Wtl[l],
                                             bs[l], (unsigned short*)xbu, nullptr, N);
    } else {
      k_gemm<<<gemmBlocks, 256, 0, stream>>>(xbu, fwdb, bwdb, Wth[l], Wtl[l],
                                             bs[l], nullptr, out, N);
    }
  }
}

// Round 3
// 468.640 us; speedup vs baseline: 1.1336x; 1.1336x over previous
//
#include <hip/hip_runtime.h>
#include <cstdint>

// ---------------------------------------------------------------------------
// DirGraphSAGE round 11:
//  - REVERT all nontemporal hints from r10: nt on the sequential ep loads
//    caused line re-fetch amplification (FETCH 222->230 MB), and nt stores on
//    fwdb/bwdb killed k_gemm's L2 hits on readback (~30us hidden cost).
//    All accesses cached again.
//  - KEEP the 4B fused edge payload (u<<16 | deg): -6.4 MB/dispatch demand,
//    weight = 1.0f/(float)deg (IEEE div, bit-identical, latency hidden under
//    the gather).  KEEP packed 16|16 ranks.
//  - NEW: edge loop unrolled x4 (was x2). k_agg6 is latency-bound (44% HBM,
//    35% VALU, 0 MFMA - nothing saturated): 4 independent gather chains per
//    thread instead of 2 raises MLP toward the BW ceiling.
// ---------------------------------------------------------------------------

typedef __bf16 bf16x8 __attribute__((ext_vector_type(8)));
typedef float f32x4 __attribute__((ext_vector_type(4)));

__device__ __forceinline__ unsigned short f2bf(float f) {
  unsigned u = __float_as_uint(f);
  u += 0x7FFFu + ((u >> 16) & 1u);   // round-to-nearest-even
  return (unsigned short)(u >> 16);
}
__device__ __forceinline__ float bflo(unsigned u) { return __uint_as_float(u << 16); }
__device__ __forceinline__ float bfhi(unsigned u) { return __uint_as_float(u & 0xFFFF0000u); }

// Padded counters: one 4B counter per 64B line (stride 16 ints).
// Ranks packed 16|16 into one array (rank < 2^16 since max degree << 2^16).
__global__ __launch_bounds__(256) void k_degrees(const int* __restrict__ src,
                                                 const int* __restrict__ dst,
                                                 int* __restrict__ cin_p,
                                                 int* __restrict__ cout_p,
                                                 unsigned* __restrict__ rank_pk, int E) {
  int e = blockIdx.x * 256 + threadIdx.x;
  if (e >= E) return;
  int s = src[e], d = dst[e];
  unsigned rf = (unsigned)atomicAdd(&cin_p[(size_t)d * 16], 1);   // rank in fwd list (by dst)
  unsigned rb = (unsigned)atomicAdd(&cout_p[(size_t)s * 16], 1);  // rank in bwd list (by src)
  rank_pk[e] = (rf & 0xFFFFu) | (rb << 16);
}

// Compact padded counters to dense arrays for the scan (inv factors no longer
// materialized: degree travels inside the edge payload).
__global__ __launch_bounds__(256) void k_compact(const int* __restrict__ cin_p,
                                                 const int* __restrict__ cout_p,
                                                 int* __restrict__ cin_d,
                                                 int* __restrict__ cout_d, int n) {
  int i = blockIdx.x * 256 + threadIdx.x;
  if (i >= n) return;
  cin_d[i] = cin_p[(size_t)i * 16];
  cout_d[i] = cout_p[(size_t)i * 16];
}

// --- 3-phase multi-block exclusive scan (CHUNK=2048/block, y-dim = which array)
__global__ __launch_bounds__(256) void k_scan_part(const int* __restrict__ cntA,
                                                   const int* __restrict__ cntB,
                                                   int* __restrict__ partA,
                                                   int* __restrict__ partB, int n) {
  const int* cnt = blockIdx.y ? cntB : cntA;
  int* part = blockIdx.y ? partB : partA;
  __shared__ int red[256];
  int t = threadIdx.x;
  int base = blockIdx.x * 2048 + t * 8;
  int s = 0;
#pragma unroll
  for (int i = 0; i < 8; ++i) {
    int idx = base + i;
    if (idx < n) s += cnt[idx];
  }
  red[t] = s;
  __syncthreads();
  for (int o = 128; o > 0; o >>= 1) {
    if (t < o) red[t] += red[t + o];
    __syncthreads();
  }
  if (t == 0) part[blockIdx.x] = red[0];
}

__global__ __launch_bounds__(64) void k_scan_tops(int* __restrict__ partA,
                                                  int* __restrict__ partB, int nb) {
  int* part = blockIdx.y ? partB : partA;
  if (threadIdx.x == 0) {
    int run = 0;
    for (int i = 0; i < nb; ++i) { int v = part[i]; part[i] = run; run += v; }
  }
}

__global__ __launch_bounds__(256) void k_scan_out(const int* __restrict__ cntA,
                                                  const int* __restrict__ cntB,
                                                  const int* __restrict__ partA,
                                                  const int* __restrict__ partB,
                                                  int* __restrict__ offA,
                                                  int* __restrict__ offB, int n) {
  const int* cnt = blockIdx.y ? cntB : cntA;
  const int* part = blockIdx.y ? partB : partA;
  int* off = blockIdx.y ? offB : offA;
  __shared__ int ts[256];
  int t = threadIdx.x;
  int base = blockIdx.x * 2048 + t * 8;
  int v[8];
  int s = 0;
#pragma unroll
  for (int i = 0; i < 8; ++i) {
    int idx = base + i;
    int c = (idx < n) ? cnt[idx] : 0;
    v[i] = s;          // exclusive prefix within thread
    s += c;
  }
  ts[t] = s;
  __syncthreads();
  for (int o = 1; o < 256; o <<= 1) {
    int val = (t >= o) ? ts[t - o] : 0;
    __syncthreads();
    ts[t] += val;
    __syncthreads();
  }
  int blockbase = part[blockIdx.x] + (t ? ts[t - 1] : 0);
#pragma unroll
  for (int i = 0; i < 8; ++i) {
    int idx = base + i;
    if (idx <= n) off[idx] = blockbase + v[i];   // idx==n writes the total
  }
}

// Atomic-free fill; writes fused 4B edge payload (u<<16 | deg(u)).
__global__ __launch_bounds__(256) void k_fill(const int* __restrict__ src,
                                              const int* __restrict__ dst,
                                              const int* __restrict__ offf,
                                              const int* __restrict__ offb,
                                              const unsigned* __restrict__ rank_pk,
                                              const int* __restrict__ cout_d,
                                              const int* __restrict__ cin_d,
                                              unsigned* __restrict__ epf,
                                              unsigned* __restrict__ epb, int E) {
  int e = blockIdx.x * 256 + threadIdx.x;
  if (e >= E) return;
  int s = src[e], d = dst[e];
  unsigned rp = rank_pk[e];
  int rf = (int)(rp & 0xFFFFu), rb = (int)(rp >> 16);
  unsigned co = (unsigned)cout_d[s]; if (co > 65535u) co = 65535u;
  unsigned ci = (unsigned)cin_d[d];  if (ci > 65535u) ci = 65535u;
  epf[offf[d] + rf] = ((unsigned)s << 16) | co;   // weight = 1/out_deg(s)
  epb[offb[s] + rb] = ((unsigned)d << 16) | ci;   // weight = 1/in_deg(d)
}

// x (fp32, N x 128) -> xbu row-major packed bf16x2 (32 uint2 per row)
__global__ __launch_bounds__(256) void k_conv(const float* __restrict__ x,
                                              unsigned* __restrict__ xbu, int n) {
  int idx = blockIdx.x * 256 + threadIdx.x;  // over n*32 float4s
  if (idx >= n * 32) return;
  float4 xv = ((const float4*)x)[idx];
  unsigned u0 = (unsigned)f2bf(xv.x) | ((unsigned)f2bf(xv.y) << 16);
  unsigned u1 = (unsigned)f2bf(xv.z) | ((unsigned)f2bf(xv.w) << 16);
  ((uint2*)xbu)[idx] = make_uint2(u0, u1);
}

// W (fp32 384x128) -> Wt_hi, Wt_lo (bf16, 128x384, transposed, packed x2)
__global__ __launch_bounds__(256) void k_wconv3(
    const float* __restrict__ Wa, const float* __restrict__ Wb,
    const float* __restrict__ Wc,
    unsigned* __restrict__ Ha, unsigned* __restrict__ Hb, unsigned* __restrict__ Hc,
    unsigned* __restrict__ La, unsigned* __restrict__ Lb, unsigned* __restrict__ Lc) {
  const float* W = (blockIdx.y == 0) ? Wa : ((blockIdx.y == 1) ? Wb : Wc);
  unsigned* Wth = (blockIdx.y == 0) ? Ha : ((blockIdx.y == 1) ? Hb : Hc);
  unsigned* Wtl = (blockIdx.y == 0) ? La : ((blockIdx.y == 1) ? Lb : Lc);
  int t = blockIdx.x * 256 + threadIdx.x;   // 128*192 threads; t = j*192 + k2
  if (t >= 128 * 192) return;
  int j = t / 192, k2 = t - j * 192;
  int k = k2 * 2;
  float w0 = W[k * 128 + j], w1 = W[(k + 1) * 128 + j];
  unsigned short h0 = f2bf(w0), h1 = f2bf(w1);
  float l0 = w0 - __uint_as_float((unsigned)h0 << 16);
  float l1 = w1 - __uint_as_float((unsigned)h1 << 16);
  Wth[t] = (unsigned)h0 | ((unsigned)h1 << 16);
  Wtl[t] = (unsigned)f2bf(l0) | ((unsigned)f2bf(l1) << 16);
}

// Single-pass row-major aggregation. 16 lanes/node (uint4 col c), 4 nodes/wave.
// grid: x = node blocks (16 nodes/block), y = dir. ep payload = (u<<16|deg);
// weight recomputed as exact fp32 divide (bit-identical to a table lookup,
// latency hidden under the gather). Edge loop unrolled x4: 4 independent
// gather chains in flight per thread (latency-bound kernel - MLP is the lever).
__global__ __launch_bounds__(256) void k_agg6(const uint4* __restrict__ xb,
                                              const int* __restrict__ offA,
                                              const unsigned* __restrict__ epA,
                                              const int* __restrict__ offB,
                                              const unsigned* __restrict__ epB,
                                              uint4* __restrict__ outA,
                                              uint4* __restrict__ outB, int n) {
  int lane = threadIdx.x & 63;
  int gi = lane >> 4, c = lane & 15;     // node-in-wave, uint4 column
  int node = ((blockIdx.x * 256 + threadIdx.x) >> 6) * 4 + gi;
  if (node >= n) return;
  const int* off = blockIdx.y ? offB : offA;
  const unsigned* ep = blockIdx.y ? epB : epA;
  uint4* out = blockIdx.y ? outB : outA;

  int i = off[node], end = off[node + 1];
  float acc[8];
#pragma unroll
  for (int k = 0; k < 8; ++k) acc[k] = 0.f;

#define AGG_BODY(r_, w_)                                                      \
  acc[0] = fmaf(bflo(r_.x), w_, acc[0]); acc[1] = fmaf(bfhi(r_.x), w_, acc[1]); \
  acc[2] = fmaf(bflo(r_.y), w_, acc[2]); acc[3] = fmaf(bfhi(r_.y), w_, acc[3]); \
  acc[4] = fmaf(bflo(r_.z), w_, acc[4]); acc[5] = fmaf(bfhi(r_.z), w_, acc[5]); \
  acc[6] = fmaf(bflo(r_.w), w_, acc[6]); acc[7] = fmaf(bfhi(r_.w), w_, acc[7]);

  for (; i + 3 < end; i += 4) {
    unsigned e0 = ep[i], e1 = ep[i + 1], e2 = ep[i + 2], e3 = ep[i + 3];
    uint4 r0 = xb[(size_t)(e0 >> 16) * 16 + c];
    uint4 r1 = xb[(size_t)(e1 >> 16) * 16 + c];
    uint4 r2 = xb[(size_t)(e2 >> 16) * 16 + c];
    uint4 r3 = xb[(size_t)(e3 >> 16) * 16 + c];
    float w0 = 1.0f / (float)(e0 & 0xFFFFu);   // IEEE div: bit-exact vs table
    float w1 = 1.0f / (float)(e1 & 0xFFFFu);
    float w2 = 1.0f / (float)(e2 & 0xFFFFu);
    float w3 = 1.0f / (float)(e3 & 0xFFFFu);
    AGG_BODY(r0, w0)
    AGG_BODY(r1, w1)
    AGG_BODY(r2, w2)
    AGG_BODY(r3, w3)
  }
  for (; i < end; ++i) {
    unsigned e0 = ep[i];
    uint4 r0 = xb[(size_t)(e0 >> 16) * 16 + c];
    float w0 = 1.0f / (float)(e0 & 0xFFFFu);
    AGG_BODY(r0, w0)
  }
#undef AGG_BODY

  uint4 o;
  o.x = (unsigned)f2bf(acc[0]) | ((unsigned)f2bf(acc[1]) << 16);
  o.y = (unsigned)f2bf(acc[2]) | ((unsigned)f2bf(acc[3]) << 16);
  o.z = (unsigned)f2bf(acc[4]) | ((unsigned)f2bf(acc[5]) << 16);
  o.w = (unsigned)f2bf(acc[6]) | ((unsigned)f2bf(acc[7]) << 16);
  out[(size_t)node * 16 + c] = o;
}

// MFMA GEMM: h = bias + [xbu|fwdb|bwdb][v,:] @ (W_hi + W_lo)   (row-major A)
// If outb: write bf16(relu(h)) row-major (next layer's xbu). Else fp32 outf.
__global__ __launch_bounds__(256) void k_gemm(const unsigned* __restrict__ xbu,
                                              const unsigned* __restrict__ fwdb,
                                              const unsigned* __restrict__ bwdb,
                                              const unsigned* __restrict__ Wth,
                                              const unsigned* __restrict__ Wtl,
                                              const float* __restrict__ bias,
                                              unsigned short* __restrict__ outb,
                                              float* __restrict__ outf, int n) {
  __shared__ uint4 sA[512];    // 8 KB: A chunk, frag order [mt][q][m]
  __shared__ uint4 sWh[512];   // 8 KB
  __shared__ uint4 sWl[512];   // 8 KB
  int tid = threadIdx.x;
  int bm0 = blockIdx.x * 128;
  int w = tid >> 6, lane = tid & 63;

  f32x4 acc[2][8];
#pragma unroll
  for (int mt = 0; mt < 2; ++mt)
#pragma unroll
    for (int nt = 0; nt < 8; ++nt) acc[mt][nt] = (f32x4){0.f, 0.f, 0.f, 0.f};

  const uint4* Wh4 = (const uint4*)Wth;   // row j: 48 uint4 (384 bf16)
  const uint4* Wl4 = (const uint4*)Wtl;

  for (int kc = 0; kc < 12; ++kc) {
    const uint4* src4 = (const uint4*)((kc < 4) ? xbu : ((kc < 8) ? fwdb : bwdb));
    int ko = (kc & 3) * 4;   // uint4 offset within row (16 uint4 = 128 bf16)
    __syncthreads();
#pragma unroll
    for (int p = 0; p < 2; ++p) {
      int f = tid + p * 256;          // 0..511
      int r = f >> 2, q = f & 3;      // r: row/col-of-W, q: k-quad
      int slot = (r >> 4) * 64 + q * 16 + (r & 15);
      int v = bm0 + r;
      uint4 val = make_uint4(0u, 0u, 0u, 0u);
      if (v < n) val = src4[(size_t)v * 16 + ko + q];
      sA[slot] = val;
      sWh[slot] = Wh4[(size_t)r * 48 + kc * 4 + q];
      sWl[slot] = Wl4[(size_t)r * 48 + kc * 4 + q];
    }
    __syncthreads();
    bf16x8 a0 = ((const bf16x8*)sA)[(2 * w) * 64 + lane];
    bf16x8 a1 = ((const bf16x8*)sA)[(2 * w + 1) * 64 + lane];
#pragma unroll
    for (int nt = 0; nt < 8; ++nt) {
      bf16x8 bh = ((const bf16x8*)sWh)[nt * 64 + lane];
      bf16x8 bl = ((const bf16x8*)sWl)[nt * 64 + lane];
      acc[0][nt] = __builtin_amdgcn_mfma_f32_16x16x32_bf16(a0, bh, acc[0][nt], 0, 0, 0);
      acc[0][nt] = __builtin_amdgcn_mfma_f32_16x16x32_bf16(a0, bl, acc[0][nt], 0, 0, 0);
      acc[1][nt] = __builtin_amdgcn_mfma_f32_16x16x32_bf16(a1, bh, acc[1][nt], 0, 0, 0);
      acc[1][nt] = __builtin_amdgcn_mfma_f32_16x16x32_bf16(a1, bl, acc[1][nt], 0, 0, 0);
    }
  }

  // Epilogue. C layout: col = lane&15, row = (lane>>4)*4 + reg  (m89-verified)
  int col = lane & 15;
  float bv[8];
#pragma unroll
  for (int nt = 0; nt < 8; ++nt) bv[nt] = bias[nt * 16 + col];
#pragma unroll
  for (int mt = 0; mt < 2; ++mt) {
    int rowbase = bm0 + w * 32 + mt * 16 + (lane >> 4) * 4;
#pragma unroll
    for (int reg = 0; reg < 4; ++reg) {
      int row = rowbase + reg;
      if (row >= n) continue;
      if (outb) {
#pragma unroll
        for (int nt = 0; nt < 8; ++nt) {
          float t = fmaxf(acc[mt][nt][reg] + bv[nt], 0.f);   // relu layers
          outb[(size_t)row * 128 + nt * 16 + col] = f2bf(t);
        }
      } else {
#pragma unroll
        for (int nt = 0; nt < 8; ++nt) {
          float t = acc[mt][nt][reg] + bv[nt];
          outf[(size_t)row * 128 + nt * 16 + col] = t;
        }
      }
    }
  }
}

extern "C" void kernel_launch(void* const* d_in, const int* in_sizes, int n_in,
                              void* d_out, int out_size, void* d_ws, size_t ws_size,
                              hipStream_t stream) {
  const int D = 128;
  const int N = in_sizes[0] / D;
  const int E = in_sizes[7];

  const float* x  = (const float*)d_in[0];
  const float* W0 = (const float*)d_in[1];
  const float* b0 = (const float*)d_in[2];
  const float* W1 = (const float*)d_in[3];
  const float* b1 = (const float*)d_in[4];
  const float* W2 = (const float*)d_in[5];
  const float* b2 = (const float*)d_in[6];
  const int* src  = (const int*)d_in[7];
  const int* dst  = (const int*)d_in[8];
  float* out = (float*)d_out;

  char* p = (char*)d_ws;
  auto alloc = [&](size_t bytes) -> char* {
    char* r = p;
    p += (bytes + 15) & ~(size_t)15;
    return r;
  };
  int* cin_p  = (int*)alloc((size_t)N * 64);   // padded: 1 counter / 64B line
  int* cout_p = (int*)alloc((size_t)N * 64);
  int* cin_d  = (int*)alloc((size_t)N * 4);    // dense for scan + payload build
  int* cout_d = (int*)alloc((size_t)N * 4);
  int* offf = (int*)alloc((size_t)(N + 1) * 4);
  int* offb = (int*)alloc((size_t)(N + 1) * 4);
  unsigned* rank_pk = (unsigned*)alloc((size_t)E * 4);   // rankf | rankb<<16
  unsigned* epf = (unsigned*)alloc((size_t)E * 4);       // (u<<16 | deg) payload
  unsigned* epb = (unsigned*)alloc((size_t)E * 4);
  unsigned* xbu = (unsigned*)alloc((size_t)N * 64 * 4);  // row-major bf16x2
  unsigned* fwdb = (unsigned*)alloc((size_t)N * 64 * 4);
  unsigned* bwdb = (unsigned*)alloc((size_t)N * 64 * 4);
  unsigned* Wth[3], *Wtl[3];
  for (int l = 0; l < 3; ++l) {
    Wth[l] = (unsigned*)alloc((size_t)128 * 192 * 4);
    Wtl[l] = (unsigned*)alloc((size_t)128 * 192 * 4);
  }
  int nbScan = (N + 1 + 2047) / 2048;
  int* partA = (int*)alloc((size_t)(nbScan + 1) * 4);
  int* partB = (int*)alloc((size_t)(nbScan + 1) * 4);

  hipMemsetAsync(cin_p, 0, (size_t)2 * N * 64, stream);  // cin_p+cout_p contiguous

  k_degrees<<<(E + 255) / 256, 256, 0, stream>>>(src, dst, cin_p, cout_p,
                                                 rank_pk, E);
  k_compact<<<(N + 255) / 256, 256, 0, stream>>>(cin_p, cout_p, cin_d, cout_d, N);
  k_scan_part<<<dim3(nbScan, 2), 256, 0, stream>>>(cin_d, cout_d, partA, partB, N);
  k_scan_tops<<<dim3(1, 2), 64, 0, stream>>>(partA, partB, nbScan);
  k_scan_out<<<dim3(nbScan, 2), 256, 0, stream>>>(cin_d, cout_d, partA, partB,
                                                  offf, offb, N);
  k_fill<<<(E + 255) / 256, 256, 0, stream>>>(src, dst, offf, offb, rank_pk,
                                              cout_d, cin_d, epf, epb, E);
  k_wconv3<<<dim3((128 * 192 + 255) / 256, 3), 256, 0, stream>>>(
      W0, W1, W2, Wth[0], Wth[1], Wth[2], Wtl[0], Wtl[1], Wtl[2]);

  const float* bs[3] = {b0, b1, b2};
  int aggBlocks = (N + 15) / 16;          // 16 nodes/block (4 waves); dir = y
  int convBlocks = (N * 32 + 255) / 256;
  int gemmBlocks = (N + 127) / 128;

  k_conv<<<convBlocks, 256, 0, stream>>>(x, xbu, N);   // layer-0 input only
  for (int l = 0; l < 3; ++l) {
    k_agg6<<<dim3(aggBlocks, 2), 256, 0, stream>>>(
        (const uint4*)xbu, offf, epf, offb, epb,
        (uint4*)fwdb, (uint4*)bwdb, N);
    if (l < 2) {
      k_gemm<<<gemmBlocks, 256, 0, stream>>>(xbu, fwdb, bwdb, Wth[l], Wtl[l],
                                             bs[l], (unsigned short*)xbu, nullptr, N);
    } else {
      k_gemm<<<gemmBlocks, 256, 0, stream>>>(xbu, fwdb, bwdb, Wth[l], Wtl[l],
                                             bs[l], nullptr, out, N);
    }
  }
}